// Round 5
// baseline (25.778 us; speedup 1.0000x reference)
//
#include <hip/hip_runtime.h>

// Tree positional embedding, closed form:
//   out[i][8*j + child_idx(ancestor_j(i))] = 1.0 for j < min(depth[i], K), else 0
// BRANCH=8, K_DEPTH=16 (h = 128 floats/row).
//
// R3 structure (best so far, 21.6us), single change: nontemporal stores.
// Block = 256 threads, 128 rows (64 KB of output).
//   Phase 1: threads 0..127 each walk one row's parent chain, pack hot columns
//            (3 bits/level) + clamped depth into a u64 code in LDS.
//   Phase 2: per-thread constants: c = tid&31 (float4 chunk), j = c>>1 (slot),
//            shift = 3j, window base r0 = 4c-8j in {0,4}. 16 unrolled
//            iterations: LDS code read (broadcast), extract, 4 cmp/cndmask,
//            one coalesced nontemporal dwordx4 store (bypasses L2 allocate ->
//            no dirty-L2 drain tail at kernel end).

#define PE_K 16
#define ROWS_PER_BLOCK 128

typedef float vf4 __attribute__((ext_vector_type(4)));

__global__ __launch_bounds__(256) void PositionalEmbedding_kernel(
    const int* __restrict__ parent,
    const int* __restrict__ child_idx,
    const int* __restrict__ depth,
    float* __restrict__ out,
    int N) {
  __shared__ unsigned long long codes[ROWS_PER_BLOCK];

  const int tid  = threadIdx.x;
  const int row0 = blockIdx.x * ROWS_PER_BLOCK;

  // ---- Phase 1: one lane per row builds the packed ancestor code ----
  if (tid < ROWS_PER_BLOCK) {
    int row = row0 + tid;
    unsigned long long code = 0;
    if (row < N) {
      int d  = depth[row];
      int dd = d < PE_K ? d : PE_K;
      int cur = row;
      for (int j = 0; j < dd; ++j) {
        int ci = child_idx[cur] & 7;
        code |= (unsigned long long)ci << (3 * j);
        cur = parent[cur];
      }
      code |= (unsigned long long)dd << 48;
    }
    codes[tid] = code;
  }
  __syncthreads();

  // ---- Phase 2: stream 128 rows x 32 float4, all constants hoisted ----
  const int c  = tid & 31;        // float4 chunk within row (constant)
  const int g  = tid >> 5;        // row-group 0..7 (constant)
  const int j  = c >> 1;          // 8-wide level slot (constant)
  const int sh = 3 * j;           // code shift (constant)
  const int r0 = 4 * c - 8 * j;   // compare window base: 0 or 4 (constant)

  vf4* p = reinterpret_cast<vf4*>(out) + ((long long)(row0 + g) * 32 + c);
  const int last_full_rl = N - row0;   // rows with rl < this are valid

  #pragma unroll
  for (int it = 0; it < ROWS_PER_BLOCK / 8; ++it) {
    int rl = it * 8 + g;
    unsigned long long code = codes[rl];
    int dd = (int)(code >> 48);
    int ci = (int)((code >> sh) & 7);
    ci = (j < dd) ? ci : 8;            // 8 = matches nothing -> zeros

    vf4 v;
    v.x = (ci == r0 + 0) ? 1.f : 0.f;
    v.y = (ci == r0 + 1) ? 1.f : 0.f;
    v.z = (ci == r0 + 2) ? 1.f : 0.f;
    v.w = (ci == r0 + 3) ? 1.f : 0.f;

    if (rl < last_full_rl) __builtin_nontemporal_store(v, p);
    p += 8 * 32;                       // advance 8 rows
  }
}

extern "C" void kernel_launch(void* const* d_in, const int* in_sizes, int n_in,
                              void* d_out, int out_size, void* d_ws, size_t ws_size,
                              hipStream_t stream) {
  const int* parent    = (const int*)d_in[0];
  const int* child_idx = (const int*)d_in[1];
  const int* depth     = (const int*)d_in[2];
  // d_in[3] = p_emb (unused), d_in[4] = n (=8), d_in[5] = k (=16)
  float* out = (float*)d_out;
  int N = in_sizes[0];

  int grid = (N + ROWS_PER_BLOCK - 1) / ROWS_PER_BLOCK;   // 1563 @ N=200k
  PositionalEmbedding_kernel<<<grid, 256, 0, stream>>>(parent, child_idx, depth, out, N);
}

// Round 6
// 22.221 us; speedup vs baseline: 1.1600x; 1.1600x over previous
//
#include <hip/hip_runtime.h>

// Tree positional embedding, closed form:
//   out[i][8*j + child_idx(ancestor_j(i))] = 1.0 for j < min(depth[i], K), else 0
// BRANCH=8, K_DEPTH=16 (h = 128 floats/row).
//
// R4 wave-autonomous structure (no LDS, no __syncthreads), single change vs
// R4: plain cached stores instead of nontemporal (R5 showed nt costs +4.2us).
//   Each 64-lane wave owns 64 consecutive rows. Every lane walks one row's
//   parent chain and packs a 4-bit field per level: child_idx (0..7) for
//   levels < depth, sentinel 8 otherwise -> 16 levels x 4 bits = u64 code,
//   pre-clamped so stores need no depth test.
//   Store phase: 32 iterations; lanes 0-31 emit row (2it) chunks 0-31,
//   lanes 32-63 row (2it+1) -> contiguous 1 KiB per wave-store. Codes are
//   pulled from the owning lane via __shfl (compile-time src lane per iter).
//   A wave begins storing the moment its own walk finishes.

#define PE_K 16

typedef float vf4 __attribute__((ext_vector_type(4)));

__global__ __launch_bounds__(256) void PositionalEmbedding_kernel(
    const int* __restrict__ parent,
    const int* __restrict__ child_idx,
    const int* __restrict__ depth,
    float* __restrict__ out,
    int N) {
  const int lane = threadIdx.x & 63;
  const int wave = threadIdx.x >> 6;
  const long long base = (long long)blockIdx.x * 256 + (long long)wave * 64;

  // ---- walk: one row per lane, pre-clamped 4-bit fields ----
  unsigned long long code = 0x8888888888888888ULL;  // sentinel 8 everywhere
  {
    int row = (int)base + lane;
    if (base < N && row < N) {
      int d  = depth[row];
      int dd = d < PE_K ? d : PE_K;
      int cur = row;
      for (int j = 0; j < dd; ++j) {
        unsigned long long ci = (unsigned long long)(child_idx[cur] & 7);
        code = (code & ~(0xFULL << (4 * j))) | (ci << (4 * j));
        cur = parent[cur];
      }
    }
  }
  unsigned int clo = (unsigned int)code;
  unsigned int chi = (unsigned int)(code >> 32);

  // ---- store: per-lane constants ----
  const int c  = lane & 31;       // float4 chunk within row
  const int g  = lane >> 5;       // 0 or 1: which of the pair of rows
  const int j  = c >> 1;          // 8-wide level slot
  const int sh = 4 * j;           // 4-bit field shift
  const int r0 = 4 * c - 8 * j;   // compare window base: 0 or 4

  vf4* p = reinterpret_cast<vf4*>(out) + (base + g) * 32 + c;
  const long long limit = (long long)N - base;  // valid local rows

  #pragma unroll
  for (int it = 0; it < 32; ++it) {
    int rl = it * 2 + g;
    unsigned int lo = __shfl(clo, rl);
    unsigned int hi = __shfl(chi, rl);
    unsigned long long cc = ((unsigned long long)hi << 32) | lo;
    int ci = (int)((cc >> sh) & 15);   // 0..7 hot child, 8 = none

    vf4 v;
    v.x = (ci == r0 + 0) ? 1.f : 0.f;
    v.y = (ci == r0 + 1) ? 1.f : 0.f;
    v.z = (ci == r0 + 2) ? 1.f : 0.f;
    v.w = (ci == r0 + 3) ? 1.f : 0.f;

    if (rl < limit) *p = v;
    p += 2 * 32;                       // advance 2 rows
  }
}

extern "C" void kernel_launch(void* const* d_in, const int* in_sizes, int n_in,
                              void* d_out, int out_size, void* d_ws, size_t ws_size,
                              hipStream_t stream) {
  const int* parent    = (const int*)d_in[0];
  const int* child_idx = (const int*)d_in[1];
  const int* depth     = (const int*)d_in[2];
  // d_in[3] = p_emb (unused), d_in[4] = n (=8), d_in[5] = k (=16)
  float* out = (float*)d_out;
  int N = in_sizes[0];

  int grid = (N + 255) / 256;   // 256 rows per block (64 per wave); 782 @ N=200k
  PositionalEmbedding_kernel<<<grid, 256, 0, stream>>>(parent, child_idx, depth, out, N);
}